// Round 1
// baseline (3258.970 us; speedup 1.0000x reference)
//
#include <hip/hip_runtime.h>

#define N_NODES 100000
#define N_EDGES 1200000
#define HIDDEN 64
#define NUM_LAYERS 3

// ---------------------------------------------------------------------------
// x[n][h] = emb[z[n]][h]
__global__ void embed_kernel(const int* __restrict__ z,
                             const float* __restrict__ emb,
                             float* __restrict__ x) {
    int t = blockIdx.x * blockDim.x + threadIdx.x;
    if (t >= N_NODES * HIDDEN) return;
    int n = t >> 6;
    int h = t & 63;
    x[t] = emb[z[n] * HIDDEN + h];
}

// ---------------------------------------------------------------------------
// agg[row[e]][:] += x[col[e]][:]   (16 lanes per edge, float4 each)
__global__ void scatter_kernel(const int* __restrict__ row,
                               const int* __restrict__ col,
                               const float* __restrict__ x,
                               float* __restrict__ agg) {
    long long t = (long long)blockIdx.x * blockDim.x + threadIdx.x;
    if (t >= (long long)N_EDGES * 16) return;
    int e = (int)(t >> 4);
    int j = ((int)t & 15) << 2;           // float offset within the row
    int c = col[e];
    int r = row[e];
    const float4 v = *reinterpret_cast<const float4*>(x + (long long)c * HIDDEN + j);
    float* dst = agg + (long long)r * HIDDEN + j;
    atomicAdd(dst + 0, v.x);
    atomicAdd(dst + 1, v.y);
    atomicAdd(dst + 2, v.z);
    atomicAdd(dst + 3, v.w);
}

// ---------------------------------------------------------------------------
// x[n][:] = relu((x[n][:] + agg[n][:]) @ W^T + b)   in place; 4 nodes/block
__global__ void linear_relu_kernel(float* __restrict__ x,
                                   const float* __restrict__ agg,
                                   const float* __restrict__ W,   // [64][64] row-major (out, in)
                                   const float* __restrict__ b) {
    __shared__ float Ws[64][65];   // +1 pad: bank = (h+k)%32 -> conflict-free
    __shared__ float bs[64];
    __shared__ float xs[4][64];

    int t = threadIdx.x;
    #pragma unroll
    for (int idx = t; idx < 4096; idx += 256)
        Ws[idx >> 6][idx & 63] = W[idx];
    if (t < 64) bs[t] = b[t];

    int ni = t >> 6;       // node within block (== wave id)
    int h  = t & 63;       // output feature (== lane)
    int n  = blockIdx.x * 4 + ni;
    xs[ni][h] = x[(long long)n * 64 + h] + agg[(long long)n * 64 + h];
    __syncthreads();

    float acc = bs[h];
    #pragma unroll
    for (int k = 0; k < 64; ++k)
        acc = fmaf(xs[ni][k], Ws[h][k], acc);   // xs broadcast; Ws 2 lanes/bank
    x[(long long)n * 64 + h] = fmaxf(acc, 0.0f);
}

// ---------------------------------------------------------------------------
extern "C" void kernel_launch(void* const* d_in, const int* in_sizes, int n_in,
                              void* d_out, int out_size, void* d_ws, size_t ws_size,
                              hipStream_t stream) {
    const int*   z          = (const int*)d_in[0];
    const int*   edge_index = (const int*)d_in[1];
    const float* emb        = (const float*)d_in[2];
    const float* W          = (const float*)d_in[3];
    const float* b          = (const float*)d_in[4];

    float* x   = (float*)d_out;                 // [N_NODES][HIDDEN] f32, in place
    float* agg = (float*)d_ws;                  // [N_NODES][HIDDEN] f32 scratch

    const int* row = edge_index;                // edge_index[0]
    const int* col = edge_index + N_EDGES;      // edge_index[1]

    const size_t xbytes = (size_t)N_NODES * HIDDEN * sizeof(float);

    embed_kernel<<<(N_NODES * HIDDEN + 255) / 256, 256, 0, stream>>>(z, emb, x);

    for (int i = 0; i < NUM_LAYERS; ++i) {
        hipMemsetAsync(agg, 0, xbytes, stream);
        scatter_kernel<<<(int)(((long long)N_EDGES * 16 + 255) / 256), 256, 0, stream>>>(
            row, col, x, agg);
        linear_relu_kernel<<<N_NODES / 4, 256, 0, stream>>>(
            x, agg, W + (size_t)i * HIDDEN * HIDDEN, b + (size_t)i * HIDDEN);
    }
}

// Round 2
// 399.250 us; speedup vs baseline: 8.1627x; 8.1627x over previous
//
#include <hip/hip_runtime.h>

#define N_NODES   100000
#define N_EDGES   1200000
#define HIDDEN    64
#define NUM_LAYERS 3
#define SCAN_BLOCK 256

// ---------------------------------------------------------------------------
// x[n][h] = emb[z[n]][h]
__global__ void embed_kernel(const int* __restrict__ z,
                             const float* __restrict__ emb,
                             float* __restrict__ x) {
    int t = blockIdx.x * blockDim.x + threadIdx.x;
    if (t >= N_NODES * HIDDEN) return;
    int n = t >> 6;
    int h = t & 63;
    x[t] = emb[z[n] * HIDDEN + h];
}

// ---------------------------------------------------------------------------
// deg[row[e]]++  (int atomics, L2-resident)
__global__ void deg_kernel(const int* __restrict__ row, int* __restrict__ deg) {
    int e = blockIdx.x * blockDim.x + threadIdx.x;
    if (e >= N_EDGES) return;
    atomicAdd(&deg[row[e]], 1);
}

// Block-level exclusive scan (Hillis-Steele) + per-block sums
__global__ void scan1_kernel(const int* __restrict__ deg, int* __restrict__ offs,
                             int* __restrict__ bsums) {
    __shared__ int tmp[SCAN_BLOCK];
    int i = blockIdx.x * SCAN_BLOCK + threadIdx.x;
    int v = (i < N_NODES) ? deg[i] : 0;
    tmp[threadIdx.x] = v;
    __syncthreads();
    for (int off = 1; off < SCAN_BLOCK; off <<= 1) {
        int t = (threadIdx.x >= off) ? tmp[threadIdx.x - off] : 0;
        __syncthreads();
        tmp[threadIdx.x] += t;
        __syncthreads();
    }
    if (i < N_NODES) offs[i] = tmp[threadIdx.x] - v;   // exclusive
    if (threadIdx.x == SCAN_BLOCK - 1) bsums[blockIdx.x] = tmp[threadIdx.x];
}

// Single-block exclusive scan of the 391 block sums (512 threads)
__global__ void scan2_kernel(int* __restrict__ bsums, int nb) {
    __shared__ int tmp[512];
    int v = (threadIdx.x < nb) ? bsums[threadIdx.x] : 0;
    tmp[threadIdx.x] = v;
    __syncthreads();
    for (int off = 1; off < 512; off <<= 1) {
        int t = (threadIdx.x >= off) ? tmp[threadIdx.x - off] : 0;
        __syncthreads();
        tmp[threadIdx.x] += t;
        __syncthreads();
    }
    if (threadIdx.x < nb) bsums[threadIdx.x] = tmp[threadIdx.x] - v;  // exclusive
}

// offs[i] += bsums[block]; also copy into cursor
__global__ void scan3_kernel(int* __restrict__ offs, const int* __restrict__ bsums,
                             int* __restrict__ cursor) {
    int i = blockIdx.x * SCAN_BLOCK + threadIdx.x;
    if (i >= N_NODES) return;
    int o = offs[i] + bsums[blockIdx.x];
    offs[i] = o;
    cursor[i] = o;
}

// csr_col[cursor[row[e]]++] = col[e]
__global__ void fill_kernel(const int* __restrict__ row, const int* __restrict__ col,
                            int* __restrict__ cursor, int* __restrict__ csr_col) {
    int e = blockIdx.x * blockDim.x + threadIdx.x;
    if (e >= N_EDGES) return;
    int p = atomicAdd(&cursor[row[e]], 1);
    csr_col[p] = col[e];
}

// ---------------------------------------------------------------------------
// Fused: aggregate (gather) + residual + linear + ReLU.
// One wave per node (lane = feature); W row held in registers per lane.
__global__ __launch_bounds__(256) void layer_kernel(
        const float* __restrict__ xin, float* __restrict__ xout,
        const int* __restrict__ offs, const int* __restrict__ csr_col,
        const float* __restrict__ W,   // [64][64] (out, in)
        const float* __restrict__ b) {
    __shared__ float Ws[64][65];   // +1 pad -> bank (lane+k)%32, 2-way = free
    __shared__ float xs[4][64];

    int t = threadIdx.x;
    for (int idx = t; idx < 4096; idx += 256)
        Ws[idx >> 6][idx & 63] = W[idx];
    __syncthreads();

    int lane = t & 63;
    int w    = t >> 6;

    float Wr[64];
    #pragma unroll
    for (int k = 0; k < 64; ++k) Wr[k] = Ws[lane][k];
    float bb = b[lane];

    int total_waves = gridDim.x * 4;
    for (int n = blockIdx.x * 4 + w; n < N_NODES; n += total_waves) {
        int s = offs[n];
        int e = (n == N_NODES - 1) ? N_EDGES : offs[n + 1];

        float acc = xin[n * 64 + lane];
        float a0 = 0.f, a1 = 0.f, a2 = 0.f, a3 = 0.f;
        int k = s;
        for (; k + 3 < e; k += 4) {      // 4 independent chains for MLP latency
            int c0 = csr_col[k], c1 = csr_col[k + 1];
            int c2 = csr_col[k + 2], c3 = csr_col[k + 3];
            a0 += xin[c0 * 64 + lane];
            a1 += xin[c1 * 64 + lane];
            a2 += xin[c2 * 64 + lane];
            a3 += xin[c3 * 64 + lane];
        }
        for (; k < e; ++k) acc += xin[csr_col[k] * 64 + lane];
        acc += (a0 + a1) + (a2 + a3);

        xs[w][lane] = acc;               // wave-synchronous exchange (same wave)

        float o = bb;
        #pragma unroll
        for (int k4 = 0; k4 < 16; ++k4) {
            float4 xv = *reinterpret_cast<const float4*>(&xs[w][k4 * 4]);
            o = fmaf(xv.x, Wr[k4 * 4 + 0], o);
            o = fmaf(xv.y, Wr[k4 * 4 + 1], o);
            o = fmaf(xv.z, Wr[k4 * 4 + 2], o);
            o = fmaf(xv.w, Wr[k4 * 4 + 3], o);
        }
        xout[n * 64 + lane] = fmaxf(o, 0.0f);
    }
}

// ---------------------------------------------------------------------------
extern "C" void kernel_launch(void* const* d_in, const int* in_sizes, int n_in,
                              void* d_out, int out_size, void* d_ws, size_t ws_size,
                              hipStream_t stream) {
    const int*   z          = (const int*)d_in[0];
    const int*   edge_index = (const int*)d_in[1];
    const float* emb        = (const float*)d_in[2];
    const float* W          = (const float*)d_in[3];
    const float* b          = (const float*)d_in[4];

    const int* row = edge_index;             // edge_index[0]
    const int* col = edge_index + N_EDGES;   // edge_index[1]

    float* x_out = (float*)d_out;            // [N][64]

    // workspace layout (all offsets multiple of 256 B)
    char* wsb = (char*)d_ws;
    float* x_buf   = (float*)wsb;                         // 25,600,000 B
    int*   csr_col = (int*)(wsb + 25600000);              //  4,800,000 B
    int*   deg     = (int*)(wsb + 30400000);              //    400,128 B
    int*   offs    = (int*)(wsb + 30800128);              //    400,128 B
    int*   cursor  = (int*)(wsb + 31200256);              //    400,128 B
    int*   bsums   = (int*)(wsb + 31600384);              //      2,048 B

    const int nb = (N_NODES + SCAN_BLOCK - 1) / SCAN_BLOCK;   // 391

    // ---- build CSR (once; edges are layer-invariant) ----
    hipMemsetAsync(deg, 0, N_NODES * sizeof(int), stream);
    deg_kernel<<<(N_EDGES + 255) / 256, 256, 0, stream>>>(row, deg);
    scan1_kernel<<<nb, SCAN_BLOCK, 0, stream>>>(deg, offs, bsums);
    scan2_kernel<<<1, 512, 0, stream>>>(bsums, nb);
    scan3_kernel<<<nb, SCAN_BLOCK, 0, stream>>>(offs, bsums, cursor);
    fill_kernel<<<(N_EDGES + 255) / 256, 256, 0, stream>>>(row, col, cursor, csr_col);

    // ---- embedding into x_buf ----
    embed_kernel<<<(N_NODES * HIDDEN + 255) / 256, 256, 0, stream>>>(z, emb, x_buf);

    // ---- 3 fused layers, ping-pong x_buf <-> d_out ----
    const int LBLOCKS = 1280;   // 5 blocks/CU, ~20 nodes per wave
    layer_kernel<<<LBLOCKS, 256, 0, stream>>>(x_buf, x_out, offs, csr_col,
                                              W + 0 * HIDDEN * HIDDEN, b + 0 * HIDDEN);
    layer_kernel<<<LBLOCKS, 256, 0, stream>>>(x_out, x_buf, offs, csr_col,
                                              W + 1 * HIDDEN * HIDDEN, b + 1 * HIDDEN);
    layer_kernel<<<LBLOCKS, 256, 0, stream>>>(x_buf, x_out, offs, csr_col,
                                              W + 2 * HIDDEN * HIDDEN, b + 2 * HIDDEN);
}